// Round 4
// baseline (499.515 us; speedup 1.0000x reference)
//
#include <hip/hip_runtime.h>
#include <hip/hip_bf16.h>

#define N_NODES 50000
#define N_EDGES 800000
#define FEAT    128
#define HID     128
#define NCLS    40

#define NPART   64              // partial-histogram blocks
#define EPB     (N_EDGES / NPART)   // 12500 edges per partial block

// ---------------- workspace layout ----------------
// part_in/part_out alias htmp: partials are dead before GEMM1 writes htmp.
static constexpr size_t ALIGNB = 256;
static constexpr size_t aln(size_t x){ return (x + ALIGNB - 1) & ~(ALIGNB - 1); }
static constexpr size_t OFF_ONORM   = 0;
static constexpr size_t OFF_INORM   = OFF_ONORM + aln((size_t)N_NODES * 4);
static constexpr size_t OFF_ROWPTR  = OFF_INORM + aln((size_t)N_NODES * 4);
static constexpr size_t OFF_DIN     = OFF_ROWPTR + aln((size_t)(N_NODES + 1) * 4);
static constexpr size_t OFF_ESRC    = OFF_DIN + aln((size_t)N_NODES * 4);
static constexpr size_t OFF_HTMP    = OFF_ESRC + aln((size_t)N_EDGES * 4);
static constexpr size_t OFF_XBUF    = OFF_HTMP + aln((size_t)N_NODES * HID * 4);
// part_in  = OFF_HTMP          (64 x 50000 u32 = 12.8 MB)
// part_out = OFF_HTMP + 12.8MB (64 x 50000 u32 = 12.8 MB)  == htmp size exactly
static constexpr size_t OFF_PART_IN  = OFF_HTMP;
static constexpr size_t OFF_PART_OUT = OFF_HTMP + (size_t)NPART * N_NODES * 4;

__device__ __forceinline__ unsigned wg_atomic_inc(unsigned* p){
  return __hip_atomic_fetch_add(p, 1u, __ATOMIC_RELAXED, __HIP_MEMORY_SCOPE_WORKGROUP);
}

// ---------------- partial histograms (workgroup-scope atomics, L2-local) ----------------
__global__ __launch_bounds__(1024) void k_part_hist(const int* __restrict__ src,
                                                    const int* __restrict__ dst,
                                                    unsigned* __restrict__ part_in,
                                                    unsigned* __restrict__ part_out){
  const int b = blockIdx.x;
  unsigned* pin  = part_in  + (size_t)b * N_NODES;
  unsigned* pout = part_out + (size_t)b * N_NODES;
  // zero own slabs (uint4; 50000 % 4 == 0)
  uint4 z = make_uint4(0,0,0,0);
  for (int i = threadIdx.x; i < N_NODES / 4; i += 1024){
    ((uint4*)pin)[i]  = z;
    ((uint4*)pout)[i] = z;
  }
  __syncthreads();
  const int lo = b * EPB;
  for (int e = lo + threadIdx.x; e < lo + EPB; e += 1024){
    wg_atomic_inc(&pin[dst[e]]);
    wg_atomic_inc(&pout[src[e]]);
  }
}

// ---------------- reduce partials -> din, norms ----------------
__global__ void k_reduce_norms(const unsigned* __restrict__ part_in,
                               const unsigned* __restrict__ part_out,
                               unsigned* __restrict__ din,
                               float* __restrict__ inorm,
                               float* __restrict__ onorm){
  int i = blockIdx.x * 256 + threadIdx.x;
  if (i >= N_NODES) return;
  unsigned si = 0, so = 0;
  #pragma unroll 8
  for (int b = 0; b < NPART; ++b){
    si += part_in [(size_t)b * N_NODES + i];
    so += part_out[(size_t)b * N_NODES + i];
  }
  din[i] = si;
  inorm[i] = rsqrtf(fmaxf((float)si, 1.0f));
  onorm[i] = rsqrtf(fmaxf((float)so, 1.0f));
}

// ---------------- single-block exclusive scan over in-degrees -> row_ptr ----------------
__global__ __launch_bounds__(1024) void k_scan(const unsigned* __restrict__ din,
                                               int* __restrict__ rowptr){
  __shared__ int wsum[16];
  __shared__ int carry_s;
  const int t = threadIdx.x;
  const int lane = t & 63;
  const int w = t >> 6;
  if (t == 0) carry_s = 0;
  __syncthreads();
  for (int base = 0; base < N_NODES; base += 1024){
    int i = base + t;
    int v = (i < N_NODES) ? (int)din[i] : 0;
    int x = v;
    #pragma unroll
    for (int off = 1; off < 64; off <<= 1){
      int y = __shfl_up(x, off, 64);
      if (lane >= off) x += y;
    }
    if (lane == 63) wsum[w] = x;
    __syncthreads();
    if (w == 0 && lane < 16){
      int s = wsum[lane];
      #pragma unroll
      for (int off = 1; off < 16; off <<= 1){
        int y = __shfl_up(s, off, 64);
        if (lane >= off) s += y;
      }
      wsum[lane] = s;
    }
    __syncthreads();
    int c = carry_s;
    int woff = (w > 0) ? wsum[w - 1] : 0;
    if (i < N_NODES) rowptr[i] = c + woff + x - v;
    __syncthreads();
    if (t == 0) carry_s = c + wsum[15];
    __syncthreads();
  }
  if (t == 0) rowptr[N_NODES] = carry_s;
}

// ---------------- transform partial counts -> per-block base cursors (in place) ----------------
__global__ void k_base(unsigned* __restrict__ part_in, const int* __restrict__ rowptr){
  int i = blockIdx.x * 256 + threadIdx.x;
  if (i >= N_NODES) return;
  unsigned run = (unsigned)rowptr[i];
  #pragma unroll 8
  for (int b = 0; b < NPART; ++b){
    size_t idx = (size_t)b * N_NODES + i;
    unsigned c = part_in[idx];
    part_in[idx] = run;
    run += c;
  }
}

// ---------------- scatter edges into CSR slots (workgroup-scope cursor bumps) ----------------
__global__ __launch_bounds__(1024) void k_scatter2(const int* __restrict__ src,
                                                   const int* __restrict__ dst,
                                                   unsigned* __restrict__ base,
                                                   int* __restrict__ esrc){
  const int b = blockIdx.x;
  unsigned* bb = base + (size_t)b * N_NODES;
  const int lo = b * EPB;
  for (int e = lo + threadIdx.x; e < lo + EPB; e += 1024){
    unsigned pos = wg_atomic_inc(&bb[dst[e]]);
    esrc[pos] = src[e];
  }
}

// ---------------- register-tiled GEMM ----------------
// out[i][c] = onorm[i] * sum_k x[i][k] * W[k][c]
// Block: 256 threads = 16 row-groups x 16 col-groups. Tile 64 rows x COLS.
template<int COLS, int WC, int OUTC>
__global__ __launch_bounds__(256) void k_gemm(const float* __restrict__ xin,
                                              const float* __restrict__ Wg,
                                              const float* __restrict__ onorm,
                                              float* __restrict__ out){
  constexpr int RN = COLS / 16;          // 8 or 4
  __shared__ __align__(16) float Xl[64][129];
  __shared__ __align__(16) float Wl[32][COLS];
  const int t = threadIdx.x;
  const int rg = t & 15;
  const int cg = t >> 4;
  const int row0 = blockIdx.x * 64;

  {
    const float4* X4 = (const float4*)xin;
    #pragma unroll
    for (int i = 0; i < 8; ++i){
      int idx = t + i * 256;
      int r = idx >> 5, q = idx & 31;
      int gr = row0 + r;
      float4 p = make_float4(0.f,0.f,0.f,0.f);
      if (gr < N_NODES) p = X4[(size_t)gr * 32 + q];
      Xl[r][q*4+0] = p.x; Xl[r][q*4+1] = p.y;
      Xl[r][q*4+2] = p.z; Xl[r][q*4+3] = p.w;
    }
  }

  float acc[4][RN];
  #pragma unroll
  for (int i = 0; i < 4; ++i)
    #pragma unroll
    for (int j = 0; j < RN; ++j) acc[i][j] = 0.f;

  const int r0 = rg * 4;
  const int c0 = cg * 4;

  for (int p = 0; p < 4; ++p){
    const int k0 = p * 32;
    __syncthreads();
    if (WC == COLS){
      const float4* W4 = (const float4*)Wg;
      constexpr int NQ = 32 * COLS / 4;
      #pragma unroll
      for (int i = 0; i < NQ / 256; ++i){
        int idx = t + i * 256;
        int k = idx / (COLS/4), q = idx % (COLS/4);
        float4 pv = W4[(size_t)(k0 + k) * (COLS/4) + q];
        *(float4*)&Wl[k][q*4] = pv;
      }
    } else {
      const float4* W4 = (const float4*)Wg;
      constexpr int NQ = 32 * COLS / 4;
      #pragma unroll
      for (int i = 0; i < NQ / 256; ++i){
        int idx = t + i * 256;
        int k = idx / (COLS/4), q = idx % (COLS/4);
        float4 pv = make_float4(0.f,0.f,0.f,0.f);
        if (q < WC/4) pv = W4[(size_t)(k0 + k) * (WC/4) + q];
        *(float4*)&Wl[k][q*4] = pv;
      }
    }
    __syncthreads();

    #pragma unroll 8
    for (int k = 0; k < 32; ++k){
      const int kk = k0 + k;
      float xv[4];
      #pragma unroll
      for (int i = 0; i < 4; ++i) xv[i] = Xl[r0 + i][kk];
      float4 wA = *(const float4*)&Wl[k][c0];
      #pragma unroll
      for (int i = 0; i < 4; ++i){
        acc[i][0] += xv[i] * wA.x;
        acc[i][1] += xv[i] * wA.y;
        acc[i][2] += xv[i] * wA.z;
        acc[i][3] += xv[i] * wA.w;
      }
      if (RN == 8){
        float4 wB = *(const float4*)&Wl[k][c0 + 64];
        #pragma unroll
        for (int i = 0; i < 4; ++i){
          acc[i][4] += xv[i] * wB.x;
          acc[i][5] += xv[i] * wB.y;
          acc[i][6] += xv[i] * wB.z;
          acc[i][7] += xv[i] * wB.w;
        }
      }
    }
  }

  #pragma unroll
  for (int i = 0; i < 4; ++i){
    int gr = row0 + r0 + i;
    if (gr >= N_NODES) continue;
    float s = onorm[gr];
    if (c0 < WC){
      float4 v = make_float4(acc[i][0]*s, acc[i][1]*s, acc[i][2]*s, acc[i][3]*s);
      *(float4*)&out[(size_t)gr * OUTC + c0] = v;
    }
    if (RN == 8){
      float4 v = make_float4(acc[i][4]*s, acc[i][5]*s, acc[i][6]*s, acc[i][7]*s);
      *(float4*)&out[(size_t)gr * OUTC + c0 + 64] = v;
    }
  }
}

// ---------------- CSR gather-aggregate + epilogue ----------------
template<int CW, int BDIM, bool RELU>
__global__ __launch_bounds__(BDIM) void k_aggregate(const float* __restrict__ htmp,
                                                    const int* __restrict__ rowptr,
                                                    const int* __restrict__ esrc,
                                                    const float* __restrict__ inorm,
                                                    const float* __restrict__ bias,
                                                    float* __restrict__ outf){
  __shared__ int es[128];
  const int node = blockIdx.x;
  const int t = threadIdx.x;
  const int start = rowptr[node], end = rowptr[node + 1];
  float a0 = 0.f, a1 = 0.f, a2 = 0.f, a3 = 0.f;
  for (int e0 = start; e0 < end; e0 += 128){
    int chunk = min(128, end - e0);
    __syncthreads();
    for (int j = t; j < chunk; j += BDIM) es[j] = esrc[e0 + j];
    __syncthreads();
    if (t < CW){
      int j = 0;
      for (; j + 4 <= chunk; j += 4){
        a0 += htmp[(size_t)es[j]     * CW + t];
        a1 += htmp[(size_t)es[j + 1] * CW + t];
        a2 += htmp[(size_t)es[j + 2] * CW + t];
        a3 += htmp[(size_t)es[j + 3] * CW + t];
      }
      for (; j < chunk; ++j)
        a0 += htmp[(size_t)es[j] * CW + t];
    }
  }
  if (t < CW){
    float y = ((a0 + a1) + (a2 + a3)) * inorm[node] + bias[t];
    if (RELU) y = fmaxf(y, 0.f);
    outf[(size_t)node * CW + t] = y;
  }
}

// ---------------- launch ----------------
extern "C" void kernel_launch(void* const* d_in, const int* in_sizes, int n_in,
                              void* d_out, int out_size, void* d_ws, size_t ws_size,
                              hipStream_t stream){
  const float* feat = (const float*)d_in[0];
  const float* W1   = (const float*)d_in[1];
  const float* b1   = (const float*)d_in[2];
  const float* W2   = (const float*)d_in[3];
  const float* b2   = (const float*)d_in[4];
  const float* W3   = (const float*)d_in[5];
  const float* b3   = (const float*)d_in[6];
  const int* src = (const int*)d_in[7];
  const int* dst = (const int*)d_in[8];
  float* out = (float*)d_out;

  char* ws = (char*)d_ws;
  float*    onorm   = (float*)   (ws + OFF_ONORM);
  float*    inorm   = (float*)   (ws + OFF_INORM);
  int*      rowptr  = (int*)     (ws + OFF_ROWPTR);
  unsigned* din     = (unsigned*)(ws + OFF_DIN);
  int*      esrc    = (int*)     (ws + OFF_ESRC);
  float*    htmp    = (float*)   (ws + OFF_HTMP);
  float*    xbuf    = (float*)   (ws + OFF_XBUF);
  unsigned* part_in  = (unsigned*)(ws + OFF_PART_IN);   // aliases htmp (dead before GEMM1)
  unsigned* part_out = (unsigned*)(ws + OFF_PART_OUT);

  const int NB = (N_NODES + 255) / 256;

  // ---- CSR build (all atomics workgroup-scope, L2-local) ----
  k_part_hist   <<<NPART, 1024, 0, stream>>>(src, dst, part_in, part_out);
  k_reduce_norms<<<NB, 256, 0, stream>>>(part_in, part_out, din, inorm, onorm);
  k_scan        <<<1, 1024, 0, stream>>>(din, rowptr);
  k_base        <<<NB, 256, 0, stream>>>(part_in, rowptr);
  k_scatter2    <<<NPART, 1024, 0, stream>>>(src, dst, part_in, esrc);

  const int GB = (N_NODES + 63) / 64;
  // layer 1
  k_gemm<128, 128, 128><<<GB, 256, 0, stream>>>(feat, W1, onorm, htmp);
  k_aggregate<128, 128, true ><<<N_NODES, 128, 0, stream>>>(htmp, rowptr, esrc, inorm, b1, xbuf);
  // layer 2
  k_gemm<128, 128, 128><<<GB, 256, 0, stream>>>(xbuf, W2, onorm, htmp);
  k_aggregate<128, 128, true ><<<N_NODES, 128, 0, stream>>>(htmp, rowptr, esrc, inorm, b2, xbuf);
  // layer 3 (40 cols padded to 64 compute)
  k_gemm<64, 40, 40><<<GB, 256, 0, stream>>>(xbuf, W3, onorm, htmp);
  k_aggregate<40, 64, false><<<N_NODES, 64, 0, stream>>>(htmp, rowptr, esrc, inorm, b3, out);
}

// Round 5
// 421.734 us; speedup vs baseline: 1.1844x; 1.1844x over previous
//
#include <hip/hip_runtime.h>
#include <hip/hip_bf16.h>

#define N_NODES 50000
#define N_EDGES 800000
#define FEAT    128
#define HID     128
#define NCLS    40

#define RANGE   12500            // nodes per LDS-histogram range (50 KB of u32)
#define NRANGE  4                // 4 * 12500 = 50000
#define NS      16               // edge slices
#define SLICE   (N_EDGES / NS)   // 50000 edges per slice

// ---------------- workspace layout ----------------
static constexpr size_t ALIGNB = 256;
static constexpr size_t aln(size_t x){ return (x + ALIGNB - 1) & ~(ALIGNB - 1); }
static constexpr size_t OFF_ONORM   = 0;
static constexpr size_t OFF_INORM   = OFF_ONORM + aln((size_t)N_NODES * 4);
static constexpr size_t OFF_ROWPTR  = OFF_INORM + aln((size_t)N_NODES * 4);
static constexpr size_t OFF_DIN     = OFF_ROWPTR + aln((size_t)(N_NODES + 1) * 4);
static constexpr size_t OFF_ESRC    = OFF_DIN + aln((size_t)N_NODES * 4);
static constexpr size_t OFF_HTMP    = OFF_ESRC + aln((size_t)N_EDGES * 4);
static constexpr size_t OFF_XBUF    = OFF_HTMP + aln((size_t)N_NODES * HID * 4);
// partial histograms alias htmp (dead before GEMM1 writes htmp):
// part[z][r][s][RANGE], z=0: in-deg (dst), z=1: out-deg (src)  -> 6.4 MB total
static constexpr size_t OFF_PART    = OFF_HTMP;

// ---------------- LDS histogram (no global atomics anywhere) ----------------
// grid = (NS, NRANGE, 2); z selects dst (in-deg) vs src (out-deg).
__global__ __launch_bounds__(1024) void k_hist_lds(const int* __restrict__ src,
                                                   const int* __restrict__ dst,
                                                   unsigned* __restrict__ part){
  __shared__ unsigned h[RANGE];
  const int s = blockIdx.x, r = blockIdx.y, z = blockIdx.z;
  const int* __restrict__ idx = z ? src : dst;
  const int lo = r * RANGE;
  for (int i = threadIdx.x; i < RANGE; i += 1024) h[i] = 0;
  __syncthreads();
  const int e0 = s * SLICE;
  for (int e = e0 + threadIdx.x; e < e0 + SLICE; e += 1024){
    int v = idx[e] - lo;
    if ((unsigned)v < RANGE) atomicAdd(&h[v], 1u);   // LDS atomic
  }
  __syncthreads();
  unsigned* p = part + (((size_t)z * NRANGE + r) * NS + s) * RANGE;
  for (int i = threadIdx.x; i < RANGE; i += 1024) p[i] = h[i];
}

// ---------------- reduce partials -> din, norms ----------------
__global__ void k_reduce_norms(const unsigned* __restrict__ part,
                               unsigned* __restrict__ din,
                               float* __restrict__ inorm,
                               float* __restrict__ onorm){
  int i = blockIdx.x * 256 + threadIdx.x;
  if (i >= N_NODES) return;
  int r = i / RANGE, off = i % RANGE;
  const unsigned* pi = part + ((size_t)r * NS) * RANGE + off;
  const unsigned* po = part + (((size_t)NRANGE + r) * NS) * RANGE + off;
  unsigned si = 0, so = 0;
  #pragma unroll
  for (int s = 0; s < NS; ++s){
    si += pi[(size_t)s * RANGE];
    so += po[(size_t)s * RANGE];
  }
  din[i] = si;
  inorm[i] = rsqrtf(fmaxf((float)si, 1.0f));
  onorm[i] = rsqrtf(fmaxf((float)so, 1.0f));
}

// ---------------- single-block exclusive scan over in-degrees -> row_ptr ----------------
__global__ __launch_bounds__(1024) void k_scan(const unsigned* __restrict__ din,
                                               int* __restrict__ rowptr){
  __shared__ int wsum[16];
  __shared__ int carry_s;
  const int t = threadIdx.x;
  const int lane = t & 63;
  const int w = t >> 6;
  if (t == 0) carry_s = 0;
  __syncthreads();
  for (int base = 0; base < N_NODES; base += 1024){
    int i = base + t;
    int v = (i < N_NODES) ? (int)din[i] : 0;
    int x = v;
    #pragma unroll
    for (int off = 1; off < 64; off <<= 1){
      int y = __shfl_up(x, off, 64);
      if (lane >= off) x += y;
    }
    if (lane == 63) wsum[w] = x;
    __syncthreads();
    if (w == 0 && lane < 16){
      int s = wsum[lane];
      #pragma unroll
      for (int off = 1; off < 16; off <<= 1){
        int y = __shfl_up(s, off, 64);
        if (lane >= off) s += y;
      }
      wsum[lane] = s;
    }
    __syncthreads();
    int c = carry_s;
    int woff = (w > 0) ? wsum[w - 1] : 0;
    if (i < N_NODES) rowptr[i] = c + woff + x - v;
    __syncthreads();
    if (t == 0) carry_s = c + wsum[15];
    __syncthreads();
  }
  if (t == 0) rowptr[N_NODES] = carry_s;
}

// ---------------- transform in-deg partials -> per-(range,slice) base cursors ----------------
__global__ void k_base(unsigned* __restrict__ part, const int* __restrict__ rowptr){
  int i = blockIdx.x * 256 + threadIdx.x;
  if (i >= N_NODES) return;
  int r = i / RANGE, off = i % RANGE;
  unsigned* p = part + ((size_t)r * NS) * RANGE + off;
  unsigned run = (unsigned)rowptr[i];
  #pragma unroll
  for (int s = 0; s < NS; ++s){
    unsigned c = p[(size_t)s * RANGE];
    p[(size_t)s * RANGE] = run;
    run += c;
  }
}

// ---------------- scatter edges into CSR slots (LDS cursor atomics) ----------------
// grid = (NS, NRANGE)
__global__ __launch_bounds__(1024) void k_scatter_lds(const int* __restrict__ src,
                                                      const int* __restrict__ dst,
                                                      const unsigned* __restrict__ part,
                                                      int* __restrict__ esrc){
  __shared__ unsigned cur[RANGE];
  const int s = blockIdx.x, r = blockIdx.y;
  const int lo = r * RANGE;
  const unsigned* p = part + ((size_t)r * NS + s) * RANGE;
  for (int i = threadIdx.x; i < RANGE; i += 1024) cur[i] = p[i];
  __syncthreads();
  const int e0 = s * SLICE;
  for (int e = e0 + threadIdx.x; e < e0 + SLICE; e += 1024){
    int v = dst[e] - lo;
    if ((unsigned)v < RANGE){
      unsigned pos = atomicAdd(&cur[v], 1u);          // LDS atomic
      esrc[pos] = src[e];
    }
  }
}

// ---------------- register-tiled GEMM ----------------
// out[i][c] = onorm[i] * sum_k x[i][k] * W[k][c]
template<int COLS, int WC, int OUTC>
__global__ __launch_bounds__(256) void k_gemm(const float* __restrict__ xin,
                                              const float* __restrict__ Wg,
                                              const float* __restrict__ onorm,
                                              float* __restrict__ out){
  constexpr int RN = COLS / 16;          // 8 or 4
  __shared__ __align__(16) float Xl[64][129];
  __shared__ __align__(16) float Wl[32][COLS];
  const int t = threadIdx.x;
  const int rg = t & 15;
  const int cg = t >> 4;
  const int row0 = blockIdx.x * 64;

  {
    const float4* X4 = (const float4*)xin;
    #pragma unroll
    for (int i = 0; i < 8; ++i){
      int idx = t + i * 256;
      int r = idx >> 5, q = idx & 31;
      int gr = row0 + r;
      float4 p = make_float4(0.f,0.f,0.f,0.f);
      if (gr < N_NODES) p = X4[(size_t)gr * 32 + q];
      Xl[r][q*4+0] = p.x; Xl[r][q*4+1] = p.y;
      Xl[r][q*4+2] = p.z; Xl[r][q*4+3] = p.w;
    }
  }

  float acc[4][RN];
  #pragma unroll
  for (int i = 0; i < 4; ++i)
    #pragma unroll
    for (int j = 0; j < RN; ++j) acc[i][j] = 0.f;

  const int r0 = rg * 4;
  const int c0 = cg * 4;

  for (int p = 0; p < 4; ++p){
    const int k0 = p * 32;
    __syncthreads();
    if (WC == COLS){
      const float4* W4 = (const float4*)Wg;
      constexpr int NQ = 32 * COLS / 4;
      #pragma unroll
      for (int i = 0; i < NQ / 256; ++i){
        int idx = t + i * 256;
        int k = idx / (COLS/4), q = idx % (COLS/4);
        float4 pv = W4[(size_t)(k0 + k) * (COLS/4) + q];
        *(float4*)&Wl[k][q*4] = pv;
      }
    } else {
      const float4* W4 = (const float4*)Wg;
      constexpr int NQ = 32 * COLS / 4;
      #pragma unroll
      for (int i = 0; i < NQ / 256; ++i){
        int idx = t + i * 256;
        int k = idx / (COLS/4), q = idx % (COLS/4);
        float4 pv = make_float4(0.f,0.f,0.f,0.f);
        if (q < WC/4) pv = W4[(size_t)(k0 + k) * (WC/4) + q];
        *(float4*)&Wl[k][q*4] = pv;
      }
    }
    __syncthreads();

    #pragma unroll 8
    for (int k = 0; k < 32; ++k){
      const int kk = k0 + k;
      float xv[4];
      #pragma unroll
      for (int i = 0; i < 4; ++i) xv[i] = Xl[r0 + i][kk];
      float4 wA = *(const float4*)&Wl[k][c0];
      #pragma unroll
      for (int i = 0; i < 4; ++i){
        acc[i][0] += xv[i] * wA.x;
        acc[i][1] += xv[i] * wA.y;
        acc[i][2] += xv[i] * wA.z;
        acc[i][3] += xv[i] * wA.w;
      }
      if (RN == 8){
        float4 wB = *(const float4*)&Wl[k][c0 + 64];
        #pragma unroll
        for (int i = 0; i < 4; ++i){
          acc[i][4] += xv[i] * wB.x;
          acc[i][5] += xv[i] * wB.y;
          acc[i][6] += xv[i] * wB.z;
          acc[i][7] += xv[i] * wB.w;
        }
      }
    }
  }

  #pragma unroll
  for (int i = 0; i < 4; ++i){
    int gr = row0 + r0 + i;
    if (gr >= N_NODES) continue;
    float s = onorm[gr];
    if (c0 < WC){
      float4 v = make_float4(acc[i][0]*s, acc[i][1]*s, acc[i][2]*s, acc[i][3]*s);
      *(float4*)&out[(size_t)gr * OUTC + c0] = v;
    }
    if (RN == 8){
      float4 v = make_float4(acc[i][4]*s, acc[i][5]*s, acc[i][6]*s, acc[i][7]*s);
      *(float4*)&out[(size_t)gr * OUTC + c0 + 64] = v;
    }
  }
}

// ---------------- CSR gather-aggregate + epilogue ----------------
template<int CW, int BDIM, bool RELU>
__global__ __launch_bounds__(BDIM) void k_aggregate(const float* __restrict__ htmp,
                                                    const int* __restrict__ rowptr,
                                                    const int* __restrict__ esrc,
                                                    const float* __restrict__ inorm,
                                                    const float* __restrict__ bias,
                                                    float* __restrict__ outf){
  __shared__ int es[128];
  const int node = blockIdx.x;
  const int t = threadIdx.x;
  const int start = rowptr[node], end = rowptr[node + 1];
  float a0 = 0.f, a1 = 0.f, a2 = 0.f, a3 = 0.f;
  for (int e0 = start; e0 < end; e0 += 128){
    int chunk = min(128, end - e0);
    __syncthreads();
    for (int j = t; j < chunk; j += BDIM) es[j] = esrc[e0 + j];
    __syncthreads();
    if (t < CW){
      int j = 0;
      for (; j + 4 <= chunk; j += 4){
        a0 += htmp[(size_t)es[j]     * CW + t];
        a1 += htmp[(size_t)es[j + 1] * CW + t];
        a2 += htmp[(size_t)es[j + 2] * CW + t];
        a3 += htmp[(size_t)es[j + 3] * CW + t];
      }
      for (; j < chunk; ++j)
        a0 += htmp[(size_t)es[j] * CW + t];
    }
  }
  if (t < CW){
    float y = ((a0 + a1) + (a2 + a3)) * inorm[node] + bias[t];
    if (RELU) y = fmaxf(y, 0.f);
    outf[(size_t)node * CW + t] = y;
  }
}

// ---------------- launch ----------------
extern "C" void kernel_launch(void* const* d_in, const int* in_sizes, int n_in,
                              void* d_out, int out_size, void* d_ws, size_t ws_size,
                              hipStream_t stream){
  const float* feat = (const float*)d_in[0];
  const float* W1   = (const float*)d_in[1];
  const float* b1   = (const float*)d_in[2];
  const float* W2   = (const float*)d_in[3];
  const float* b2   = (const float*)d_in[4];
  const float* W3   = (const float*)d_in[5];
  const float* b3   = (const float*)d_in[6];
  const int* src = (const int*)d_in[7];
  const int* dst = (const int*)d_in[8];
  float* out = (float*)d_out;

  char* ws = (char*)d_ws;
  float*    onorm   = (float*)   (ws + OFF_ONORM);
  float*    inorm   = (float*)   (ws + OFF_INORM);
  int*      rowptr  = (int*)     (ws + OFF_ROWPTR);
  unsigned* din     = (unsigned*)(ws + OFF_DIN);
  int*      esrc    = (int*)     (ws + OFF_ESRC);
  float*    htmp    = (float*)   (ws + OFF_HTMP);
  float*    xbuf    = (float*)   (ws + OFF_XBUF);
  unsigned* part    = (unsigned*)(ws + OFF_PART);   // aliases htmp (dead before GEMM1)

  const int NB = (N_NODES + 255) / 256;

  // ---- CSR build: LDS atomics only ----
  k_hist_lds    <<<dim3(NS, NRANGE, 2), 1024, 0, stream>>>(src, dst, part);
  k_reduce_norms<<<NB, 256, 0, stream>>>(part, din, inorm, onorm);
  k_scan        <<<1, 1024, 0, stream>>>(din, rowptr);
  k_base        <<<NB, 256, 0, stream>>>(part, rowptr);
  k_scatter_lds <<<dim3(NS, NRANGE), 1024, 0, stream>>>(src, dst, part, esrc);

  const int GB = (N_NODES + 63) / 64;
  // layer 1
  k_gemm<128, 128, 128><<<GB, 256, 0, stream>>>(feat, W1, onorm, htmp);
  k_aggregate<128, 128, true ><<<N_NODES, 128, 0, stream>>>(htmp, rowptr, esrc, inorm, b1, xbuf);
  // layer 2
  k_gemm<128, 128, 128><<<GB, 256, 0, stream>>>(xbuf, W2, onorm, htmp);
  k_aggregate<128, 128, true ><<<N_NODES, 128, 0, stream>>>(htmp, rowptr, esrc, inorm, b2, xbuf);
  // layer 3 (40 cols padded to 64 compute)
  k_gemm<64, 40, 40><<<GB, 256, 0, stream>>>(xbuf, W3, onorm, htmp);
  k_aggregate<40, 64, false><<<N_NODES, 64, 0, stream>>>(htmp, rowptr, esrc, inorm, b3, out);
}

// Round 6
// 379.932 us; speedup vs baseline: 1.3147x; 1.1100x over previous
//
#include <hip/hip_runtime.h>
#include <hip/hip_bf16.h>

#define N_NODES 50000
#define N_EDGES 800000
#define FEAT    128
#define HID     128
#define NCLS    40

#define RANGE   12500            // nodes per LDS-histogram range (50 KB of u32)
#define NRANGE  4                // 4 * 12500 = 50000
#define NS      16               // edge slices
#define SLICE   (N_EDGES / NS)   // 50000 edges per slice

// ---------------- workspace layout ----------------
static constexpr size_t ALIGNB = 256;
static constexpr size_t aln(size_t x){ return (x + ALIGNB - 1) & ~(ALIGNB - 1); }
static constexpr size_t OFF_ONORM   = 0;
static constexpr size_t OFF_INORM   = OFF_ONORM + aln((size_t)N_NODES * 4);
static constexpr size_t OFF_ROWPTR  = OFF_INORM + aln((size_t)N_NODES * 4);
static constexpr size_t OFF_DIN     = OFF_ROWPTR + aln((size_t)(N_NODES + 1) * 4);
static constexpr size_t OFF_ESRC    = OFF_DIN + aln((size_t)N_NODES * 4);
static constexpr size_t OFF_HTMP    = OFF_ESRC + aln((size_t)N_EDGES * 4);   // bf16: 12.8 MB
static constexpr size_t OFF_XBUF    = OFF_HTMP + aln((size_t)N_NODES * HID * 2);
// partial histograms alias htmp (dead before GEMM1 writes htmp): 6.4 MB < 12.8 MB
static constexpr size_t OFF_PART    = OFF_HTMP;

// ---------------- helpers ----------------
__device__ __forceinline__ float bflo(unsigned u){
  union { unsigned i; float f; } c; c.i = u << 16; return c.f;
}
__device__ __forceinline__ float bfhi(unsigned u){
  union { unsigned i; float f; } c; c.i = u & 0xffff0000u; return c.f;
}
__device__ __forceinline__ unsigned pkbf(float a, float b){
  union { __hip_bfloat16 h; unsigned short u; } ca, cb;
  ca.h = __float2bfloat16(a); cb.h = __float2bfloat16(b);
  return ((unsigned)cb.u << 16) | (unsigned)ca.u;
}

// ---------------- LDS histogram (no global atomics anywhere) ----------------
// grid = (NS, NRANGE, 2); z selects dst (in-deg) vs src (out-deg).
__global__ __launch_bounds__(1024) void k_hist_lds(const int* __restrict__ src,
                                                   const int* __restrict__ dst,
                                                   unsigned* __restrict__ part){
  __shared__ unsigned h[RANGE];
  const int s = blockIdx.x, r = blockIdx.y, z = blockIdx.z;
  const int* __restrict__ idx = z ? src : dst;
  const int lo = r * RANGE;
  for (int i = threadIdx.x; i < RANGE; i += 1024) h[i] = 0;
  __syncthreads();
  const int e0 = s * SLICE;
  for (int e = e0 + threadIdx.x; e < e0 + SLICE; e += 1024){
    int v = idx[e] - lo;
    if ((unsigned)v < RANGE) atomicAdd(&h[v], 1u);   // LDS atomic
  }
  __syncthreads();
  unsigned* p = part + (((size_t)z * NRANGE + r) * NS + s) * RANGE;
  for (int i = threadIdx.x; i < RANGE; i += 1024) p[i] = h[i];
}

// ---------------- reduce partials -> din, norms ----------------
__global__ void k_reduce_norms(const unsigned* __restrict__ part,
                               unsigned* __restrict__ din,
                               float* __restrict__ inorm,
                               float* __restrict__ onorm){
  int i = blockIdx.x * 256 + threadIdx.x;
  if (i >= N_NODES) return;
  int r = i / RANGE, off = i % RANGE;
  const unsigned* pi = part + ((size_t)r * NS) * RANGE + off;
  const unsigned* po = part + (((size_t)NRANGE + r) * NS) * RANGE + off;
  unsigned si = 0, so = 0;
  #pragma unroll
  for (int s = 0; s < NS; ++s){
    si += pi[(size_t)s * RANGE];
    so += po[(size_t)s * RANGE];
  }
  din[i] = si;
  inorm[i] = rsqrtf(fmaxf((float)si, 1.0f));
  onorm[i] = rsqrtf(fmaxf((float)so, 1.0f));
}

// ---------------- single-block exclusive scan over in-degrees -> row_ptr ----------------
__global__ __launch_bounds__(1024) void k_scan(const unsigned* __restrict__ din,
                                               int* __restrict__ rowptr){
  __shared__ int wsum[16];
  __shared__ int carry_s;
  const int t = threadIdx.x;
  const int lane = t & 63;
  const int w = t >> 6;
  if (t == 0) carry_s = 0;
  __syncthreads();
  for (int base = 0; base < N_NODES; base += 1024){
    int i = base + t;
    int v = (i < N_NODES) ? (int)din[i] : 0;
    int x = v;
    #pragma unroll
    for (int off = 1; off < 64; off <<= 1){
      int y = __shfl_up(x, off, 64);
      if (lane >= off) x += y;
    }
    if (lane == 63) wsum[w] = x;
    __syncthreads();
    if (w == 0 && lane < 16){
      int s = wsum[lane];
      #pragma unroll
      for (int off = 1; off < 16; off <<= 1){
        int y = __shfl_up(s, off, 64);
        if (lane >= off) s += y;
      }
      wsum[lane] = s;
    }
    __syncthreads();
    int c = carry_s;
    int woff = (w > 0) ? wsum[w - 1] : 0;
    if (i < N_NODES) rowptr[i] = c + woff + x - v;
    __syncthreads();
    if (t == 0) carry_s = c + wsum[15];
    __syncthreads();
  }
  if (t == 0) rowptr[N_NODES] = carry_s;
}

// ---------------- transform in-deg partials -> per-(range,slice) base cursors ----------------
__global__ void k_base(unsigned* __restrict__ part, const int* __restrict__ rowptr){
  int i = blockIdx.x * 256 + threadIdx.x;
  if (i >= N_NODES) return;
  int r = i / RANGE, off = i % RANGE;
  unsigned* p = part + ((size_t)r * NS) * RANGE + off;
  unsigned run = (unsigned)rowptr[i];
  #pragma unroll
  for (int s = 0; s < NS; ++s){
    unsigned c = p[(size_t)s * RANGE];
    p[(size_t)s * RANGE] = run;
    run += c;
  }
}

// ---------------- scatter edges into CSR slots (LDS cursor atomics) ----------------
// grid = (NS, NRANGE)
__global__ __launch_bounds__(1024) void k_scatter_lds(const int* __restrict__ src,
                                                      const int* __restrict__ dst,
                                                      const unsigned* __restrict__ part,
                                                      int* __restrict__ esrc){
  __shared__ unsigned cur[RANGE];
  const int s = blockIdx.x, r = blockIdx.y;
  const int lo = r * RANGE;
  const unsigned* p = part + ((size_t)r * NS + s) * RANGE;
  for (int i = threadIdx.x; i < RANGE; i += 1024) cur[i] = p[i];
  __syncthreads();
  const int e0 = s * SLICE;
  for (int e = e0 + threadIdx.x; e < e0 + SLICE; e += 1024){
    int v = dst[e] - lo;
    if ((unsigned)v < RANGE){
      unsigned pos = atomicAdd(&cur[v], 1u);          // LDS atomic
      esrc[pos] = src[e];
    }
  }
}

// ---------------- register-tiled GEMM (fp32 math, bf16-packed output) ----------------
// outu32[(i*OUTC + c)/2] packs cols {c, c+1}; value = onorm[i] * sum_k x[i][k] * W[k][c]
template<int COLS, int WC, int OUTC>
__global__ __launch_bounds__(256) void k_gemm(const float* __restrict__ xin,
                                              const float* __restrict__ Wg,
                                              const float* __restrict__ onorm,
                                              unsigned* __restrict__ out){
  constexpr int RN = COLS / 16;          // 8 or 4
  __shared__ __align__(16) float Xl[64][129];
  __shared__ __align__(16) float Wl[32][COLS];
  const int t = threadIdx.x;
  const int rg = t & 15;
  const int cg = t >> 4;
  const int row0 = blockIdx.x * 64;

  {
    const float4* X4 = (const float4*)xin;
    #pragma unroll
    for (int i = 0; i < 8; ++i){
      int idx = t + i * 256;
      int r = idx >> 5, q = idx & 31;
      int gr = row0 + r;
      float4 p = make_float4(0.f,0.f,0.f,0.f);
      if (gr < N_NODES) p = X4[(size_t)gr * 32 + q];
      Xl[r][q*4+0] = p.x; Xl[r][q*4+1] = p.y;
      Xl[r][q*4+2] = p.z; Xl[r][q*4+3] = p.w;
    }
  }

  float acc[4][RN];
  #pragma unroll
  for (int i = 0; i < 4; ++i)
    #pragma unroll
    for (int j = 0; j < RN; ++j) acc[i][j] = 0.f;

  const int r0 = rg * 4;
  const int c0 = cg * 4;

  for (int p = 0; p < 4; ++p){
    const int k0 = p * 32;
    __syncthreads();
    if (WC == COLS){
      const float4* W4 = (const float4*)Wg;
      constexpr int NQ = 32 * COLS / 4;
      #pragma unroll
      for (int i = 0; i < NQ / 256; ++i){
        int idx = t + i * 256;
        int k = idx / (COLS/4), q = idx % (COLS/4);
        float4 pv = W4[(size_t)(k0 + k) * (COLS/4) + q];
        *(float4*)&Wl[k][q*4] = pv;
      }
    } else {
      const float4* W4 = (const float4*)Wg;
      constexpr int NQ = 32 * COLS / 4;
      #pragma unroll
      for (int i = 0; i < NQ / 256; ++i){
        int idx = t + i * 256;
        int k = idx / (COLS/4), q = idx % (COLS/4);
        float4 pv = make_float4(0.f,0.f,0.f,0.f);
        if (q < WC/4) pv = W4[(size_t)(k0 + k) * (WC/4) + q];
        *(float4*)&Wl[k][q*4] = pv;
      }
    }
    __syncthreads();

    #pragma unroll 8
    for (int k = 0; k < 32; ++k){
      const int kk = k0 + k;
      float xv[4];
      #pragma unroll
      for (int i = 0; i < 4; ++i) xv[i] = Xl[r0 + i][kk];
      float4 wA = *(const float4*)&Wl[k][c0];
      #pragma unroll
      for (int i = 0; i < 4; ++i){
        acc[i][0] += xv[i] * wA.x;
        acc[i][1] += xv[i] * wA.y;
        acc[i][2] += xv[i] * wA.z;
        acc[i][3] += xv[i] * wA.w;
      }
      if (RN == 8){
        float4 wB = *(const float4*)&Wl[k][c0 + 64];
        #pragma unroll
        for (int i = 0; i < 4; ++i){
          acc[i][4] += xv[i] * wB.x;
          acc[i][5] += xv[i] * wB.y;
          acc[i][6] += xv[i] * wB.z;
          acc[i][7] += xv[i] * wB.w;
        }
      }
    }
  }

  #pragma unroll
  for (int i = 0; i < 4; ++i){
    int gr = row0 + r0 + i;
    if (gr >= N_NODES) continue;
    float s = onorm[gr];
    if (c0 < WC){
      uint2 v;
      v.x = pkbf(acc[i][0]*s, acc[i][1]*s);
      v.y = pkbf(acc[i][2]*s, acc[i][3]*s);
      *(uint2*)&out[((size_t)gr * OUTC + c0) >> 1] = v;
    }
    if (RN == 8){
      uint2 v;
      v.x = pkbf(acc[i][4]*s, acc[i][5]*s);
      v.y = pkbf(acc[i][6]*s, acc[i][7]*s);
      *(uint2*)&out[((size_t)gr * OUTC + c0 + 64) >> 1] = v;
    }
  }
}

// ---------------- wave-per-node bf16 gather-aggregate ----------------
// htmp rows are CW bf16 (CU = CW/2 u32); lane l owns cols {2l, 2l+1}.
template<int CW, bool RELU>
__global__ __launch_bounds__(256) void k_agg(const unsigned* __restrict__ htmp,
                                             const int* __restrict__ rowptr,
                                             const int* __restrict__ esrc,
                                             const float* __restrict__ inorm,
                                             const float* __restrict__ bias,
                                             float* __restrict__ outf){
  constexpr int CU = CW / 2;              // 64 or 20
  const int wave = threadIdx.x >> 6;
  const int lane = threadIdx.x & 63;
  const int node = blockIdx.x * 4 + wave;
  if (node >= N_NODES) return;
  const int start = rowptr[node], end = rowptr[node + 1];
  float a0 = 0.f, a1 = 0.f, b0 = 0.f, b1 = 0.f,
        c0 = 0.f, c1 = 0.f, d0 = 0.f, d1 = 0.f;
  for (int e0 = start; e0 < end; e0 += 64){
    const int n = min(64, end - e0);
    int el = (lane < n) ? esrc[e0 + lane] : 0;
    int j = 0;
    for (; j + 4 <= n; j += 4){
      int s0 = __shfl(el, j);
      int s1 = __shfl(el, j + 1);
      int s2 = __shfl(el, j + 2);
      int s3 = __shfl(el, j + 3);
      if (lane < CU){
        unsigned u0 = htmp[(size_t)s0 * CU + lane];
        unsigned u1 = htmp[(size_t)s1 * CU + lane];
        unsigned u2 = htmp[(size_t)s2 * CU + lane];
        unsigned u3 = htmp[(size_t)s3 * CU + lane];
        a0 += bflo(u0); a1 += bfhi(u0);
        b0 += bflo(u1); b1 += bfhi(u1);
        c0 += bflo(u2); c1 += bfhi(u2);
        d0 += bflo(u3); d1 += bfhi(u3);
      }
    }
    for (; j < n; ++j){
      int s0 = __shfl(el, j);
      if (lane < CU){
        unsigned u0 = htmp[(size_t)s0 * CU + lane];
        a0 += bflo(u0); a1 += bfhi(u0);
      }
    }
  }
  if (lane < CU){
    float sc = inorm[node];
    float y0 = ((a0 + b0) + (c0 + d0)) * sc + bias[2 * lane];
    float y1 = ((a1 + b1) + (c1 + d1)) * sc + bias[2 * lane + 1];
    if (RELU){ y0 = fmaxf(y0, 0.f); y1 = fmaxf(y1, 0.f); }
    float2 v; v.x = y0; v.y = y1;
    *(float2*)&outf[(size_t)node * CW + 2 * lane] = v;
  }
}

// ---------------- launch ----------------
extern "C" void kernel_launch(void* const* d_in, const int* in_sizes, int n_in,
                              void* d_out, int out_size, void* d_ws, size_t ws_size,
                              hipStream_t stream){
  const float* feat = (const float*)d_in[0];
  const float* W1   = (const float*)d_in[1];
  const float* b1   = (const float*)d_in[2];
  const float* W2   = (const float*)d_in[3];
  const float* b2   = (const float*)d_in[4];
  const float* W3   = (const float*)d_in[5];
  const float* b3   = (const float*)d_in[6];
  const int* src = (const int*)d_in[7];
  const int* dst = (const int*)d_in[8];
  float* out = (float*)d_out;

  char* ws = (char*)d_ws;
  float*    onorm   = (float*)   (ws + OFF_ONORM);
  float*    inorm   = (float*)   (ws + OFF_INORM);
  int*      rowptr  = (int*)     (ws + OFF_ROWPTR);
  unsigned* din     = (unsigned*)(ws + OFF_DIN);
  int*      esrc    = (int*)     (ws + OFF_ESRC);
  unsigned* htmp    = (unsigned*)(ws + OFF_HTMP);   // bf16 pairs
  float*    xbuf    = (float*)   (ws + OFF_XBUF);
  unsigned* part    = (unsigned*)(ws + OFF_PART);   // aliases htmp (dead before GEMM1)

  const int NB = (N_NODES + 255) / 256;

  // ---- CSR build: LDS atomics only ----
  k_hist_lds    <<<dim3(NS, NRANGE, 2), 1024, 0, stream>>>(src, dst, part);
  k_reduce_norms<<<NB, 256, 0, stream>>>(part, din, inorm, onorm);
  k_scan        <<<1, 1024, 0, stream>>>(din, rowptr);
  k_base        <<<NB, 256, 0, stream>>>(part, rowptr);
  k_scatter_lds <<<dim3(NS, NRANGE), 1024, 0, stream>>>(src, dst, part, esrc);

  const int GB = (N_NODES + 63) / 64;
  const int AB = (N_NODES + 3) / 4;
  // layer 1
  k_gemm<128, 128, 128><<<GB, 256, 0, stream>>>(feat, W1, onorm, htmp);
  k_agg<128, true ><<<AB, 256, 0, stream>>>(htmp, rowptr, esrc, inorm, b1, xbuf);
  // layer 2
  k_gemm<128, 128, 128><<<GB, 256, 0, stream>>>(xbuf, W2, onorm, htmp);
  k_agg<128, true ><<<AB, 256, 0, stream>>>(htmp, rowptr, esrc, inorm, b2, xbuf);
  // layer 3 (40 cols padded to 64 compute)
  k_gemm<64, 40, 40><<<GB, 256, 0, stream>>>(xbuf, W3, onorm, htmp);
  k_agg<40, false><<<AB, 256, 0, stream>>>(htmp, rowptr, esrc, inorm, b3, out);
}

// Round 8
// 279.394 us; speedup vs baseline: 1.7879x; 1.3598x over previous
//
#include <hip/hip_runtime.h>
#include <hip/hip_bf16.h>

#define N_NODES 50000
#define N_EDGES 800000
#define FEAT    128
#define HID     128
#define NCLS    40
#define XPAD    50048            // N rounded up to 64 (GEMM tiles read unguarded)

#define RANGE   12500            // nodes per LDS-histogram range (50 KB of u32)
#define NRANGE  4                // 4 * 12500 = 50000
#define NS      16               // edge slices
#define SLICE   (N_EDGES / NS)   // 50000 edges per slice
#define NBLK    49               // scan blocks: ceil(50000/1024)

// ---------------- workspace layout ----------------
static constexpr size_t ALIGNB = 256;
static constexpr size_t aln(size_t x){ return (x + ALIGNB - 1) & ~(ALIGNB - 1); }
static constexpr size_t OFF_ONORM   = 0;
static constexpr size_t OFF_INORM   = OFF_ONORM + aln((size_t)N_NODES * 4);
static constexpr size_t OFF_ROWPTR  = OFF_INORM + aln((size_t)N_NODES * 4);
static constexpr size_t OFF_DIN     = OFF_ROWPTR + aln((size_t)(N_NODES + 1) * 4);
static constexpr size_t OFF_BSUM    = OFF_DIN + aln((size_t)N_NODES * 4);
static constexpr size_t OFF_BOFF    = OFF_BSUM + aln(64 * 4);
static constexpr size_t OFF_WT1     = OFF_BOFF + aln(64 * 4);
static constexpr size_t OFF_WT2     = OFF_WT1 + aln((size_t)128 * 128 * 2);
static constexpr size_t OFF_WT3     = OFF_WT2 + aln((size_t)128 * 128 * 2);
static constexpr size_t OFF_ESRC    = OFF_WT3 + aln((size_t)64 * 128 * 2);
static constexpr size_t OFF_FEATB   = OFF_ESRC + aln((size_t)N_EDGES * 4);
static constexpr size_t OFF_HTMP    = OFF_FEATB + aln((size_t)XPAD * 128 * 2);
static constexpr size_t OFF_XBUF    = OFF_HTMP + aln((size_t)XPAD * 128 * 2);
// partial histograms alias htmp (dead before GEMM1 writes htmp): 6.4 MB < 12.8 MB
static constexpr size_t OFF_PART    = OFF_HTMP;

// ---------------- helpers ----------------
__device__ __forceinline__ float bflo(unsigned u){
  union { unsigned i; float f; } c; c.i = u << 16; return c.f;
}
__device__ __forceinline__ float bfhi(unsigned u){
  union { unsigned i; float f; } c; c.i = u & 0xffff0000u; return c.f;
}
__device__ __forceinline__ unsigned pkbf(float a, float b){
  union { __hip_bfloat16 h; unsigned short u; } ca, cb;
  ca.h = __float2bfloat16(a); cb.h = __float2bfloat16(b);
  return ((unsigned)cb.u << 16) | (unsigned)ca.u;
}
__device__ __forceinline__ unsigned short bf1(float a){
  union { __hip_bfloat16 h; unsigned short u; } c;
  c.h = __float2bfloat16(a); return c.u;
}

typedef __attribute__((ext_vector_type(8))) short bf16x8;
typedef __attribute__((ext_vector_type(4))) float f32x4;

// ---------------- fp32 -> packed bf16 conversion (feat) ----------------
// one float4 -> uint2 per thread; grid covers 50000*128/4 = 1.6M float4 exactly
__global__ void k_cvt(const float* __restrict__ x, unsigned* __restrict__ o){
  int i = blockIdx.x * 256 + threadIdx.x;
  float4 v = ((const float4*)x)[i];
  uint2 r; r.x = pkbf(v.x, v.y); r.y = pkbf(v.z, v.w);
  ((uint2*)o)[i] = r;
}

// ---------------- W[k][c] fp32 -> Wt[c][k] bf16 (zero-pad cols >= WC) ----------------
template<int WC, int CTC>
__global__ void k_prep_w(const float* __restrict__ W, unsigned* __restrict__ Wt){
  int idx = blockIdx.x * 256 + threadIdx.x;  // over CTC*16*64 u32 (c-major, k-pairs)
  if (idx >= CTC * 16 * 64) return;
  int c = idx >> 6, kp = idx & 63;
  float v0 = (c < WC) ? W[(size_t)(2 * kp)     * WC + c] : 0.f;
  float v1 = (c < WC) ? W[(size_t)(2 * kp + 1) * WC + c] : 0.f;
  Wt[idx] = pkbf(v0, v1);
}

// ---------------- LDS histogram (no global atomics anywhere) ----------------
// grid = (NS, NRANGE, 2); z selects dst (in-deg) vs src (out-deg).
__global__ __launch_bounds__(1024) void k_hist_lds(const int* __restrict__ src,
                                                   const int* __restrict__ dst,
                                                   unsigned* __restrict__ part){
  __shared__ unsigned h[RANGE];
  const int s = blockIdx.x, r = blockIdx.y, z = blockIdx.z;
  const int* __restrict__ idx = z ? src : dst;
  const int lo = r * RANGE;
  for (int i = threadIdx.x; i < RANGE; i += 1024) h[i] = 0;
  __syncthreads();
  const int e0 = s * SLICE;
  for (int e = e0 + threadIdx.x; e < e0 + SLICE; e += 1024){
    int v = idx[e] - lo;
    if ((unsigned)v < RANGE) atomicAdd(&h[v], 1u);   // LDS atomic
  }
  __syncthreads();
  unsigned* p = part + (((size_t)z * NRANGE + r) * NS + s) * RANGE;
  for (int i = threadIdx.x; i < RANGE; i += 1024) p[i] = h[i];
}

// ---------------- reduce partials -> din, norms ----------------
__global__ void k_reduce_norms(const unsigned* __restrict__ part,
                               unsigned* __restrict__ din,
                               float* __restrict__ inorm,
                               float* __restrict__ onorm){
  int i = blockIdx.x * 256 + threadIdx.x;
  if (i >= N_NODES) return;
  int r = i / RANGE, off = i % RANGE;
  const unsigned* pi = part + ((size_t)r * NS) * RANGE + off;
  const unsigned* po = part + (((size_t)NRANGE + r) * NS) * RANGE + off;
  unsigned si = 0, so = 0;
  #pragma unroll
  for (int s = 0; s < NS; ++s){
    si += pi[(size_t)s * RANGE];
    so += po[(size_t)s * RANGE];
  }
  din[i] = si;
  inorm[i] = rsqrtf(fmaxf((float)si, 1.0f));
  onorm[i] = rsqrtf(fmaxf((float)so, 1.0f));
}

// ---------------- hierarchical scan: local block scans ----------------
__global__ __launch_bounds__(1024) void k_scan1(const unsigned* __restrict__ din,
                                                int* __restrict__ rowptr,
                                                unsigned* __restrict__ bsum){
  __shared__ int wsum[16];
  const int t = threadIdx.x, lane = t & 63, w = t >> 6;
  const int i = blockIdx.x * 1024 + t;
  int v = (i < N_NODES) ? (int)din[i] : 0;
  int x = v;
  #pragma unroll
  for (int off = 1; off < 64; off <<= 1){
    int y = __shfl_up(x, off, 64);
    if (lane >= off) x += y;
  }
  if (lane == 63) wsum[w] = x;
  __syncthreads();
  if (w == 0 && lane < 16){
    int s = wsum[lane];
    #pragma unroll
    for (int off = 1; off < 16; off <<= 1){
      int y = __shfl_up(s, off, 64);
      if (lane >= off) s += y;
    }
    wsum[lane] = s;
  }
  __syncthreads();
  int woff = (w > 0) ? wsum[w - 1] : 0;
  if (i < N_NODES) rowptr[i] = woff + x - v;
  if (t == 0) bsum[blockIdx.x] = (unsigned)wsum[15];
}

// ---------------- scan of block sums (single wave) ----------------
__global__ void k_scan2(const unsigned* __restrict__ bsum, unsigned* __restrict__ boff){
  const int t = threadIdx.x;                 // 64 threads
  int v = (t < NBLK) ? (int)bsum[t] : 0;
  int x = v;
  #pragma unroll
  for (int off = 1; off < 64; off <<= 1){
    int y = __shfl_up(x, off, 64);
    if (t >= off) x += y;
  }
  if (t < NBLK) boff[t] = (unsigned)(x - v);
  if (t == NBLK - 1) boff[NBLK] = (unsigned)x;   // grand total
}

// ---------------- add block offsets ----------------
__global__ __launch_bounds__(1024) void k_scan3(int* __restrict__ rowptr,
                                                const unsigned* __restrict__ boff){
  const int i = blockIdx.x * 1024 + threadIdx.x;
  if (i < N_NODES) rowptr[i] += (int)boff[blockIdx.x];
  else if (i == N_NODES) rowptr[i] = (int)boff[NBLK];
}

// ---------------- transform in-deg partials -> per-(range,slice) base cursors ----------------
__global__ void k_base(unsigned* __restrict__ part, const int* __restrict__ rowptr){
  int i = blockIdx.x * 256 + threadIdx.x;
  if (i >= N_NODES) return;
  int r = i / RANGE, off = i % RANGE;
  unsigned* p = part + ((size_t)r * NS) * RANGE + off;
  unsigned run = (unsigned)rowptr[i];
  #pragma unroll
  for (int s = 0; s < NS; ++s){
    unsigned c = p[(size_t)s * RANGE];
    p[(size_t)s * RANGE] = run;
    run += c;
  }
}

// ---------------- scatter edges into CSR slots (LDS cursor atomics) ----------------
// grid = (NS, NRANGE)
__global__ __launch_bounds__(1024) void k_scatter_lds(const int* __restrict__ src,
                                                      const int* __restrict__ dst,
                                                      const unsigned* __restrict__ part,
                                                      int* __restrict__ esrc){
  __shared__ unsigned cur[RANGE];
  const int s = blockIdx.x, r = blockIdx.y;
  const int lo = r * RANGE;
  const unsigned* p = part + ((size_t)r * NS + s) * RANGE;
  for (int i = threadIdx.x; i < RANGE; i += 1024) cur[i] = p[i];
  __syncthreads();
  const int e0 = s * SLICE;
  for (int e = e0 + threadIdx.x; e < e0 + SLICE; e += 1024){
    int v = dst[e] - lo;
    if ((unsigned)v < RANGE){
      unsigned pos = atomicAdd(&cur[v], 1u);          // LDS atomic
      esrc[pos] = src[e];
    }
  }
}

// ---------------- MFMA GEMM: out[r][c] = bf16( onorm[r] * sum_k X[r][k] * W[k][c] ) ----------------
// X: bf16 [XPAD][128] row-major. Wt: bf16 [CT*16][128] (c-major). Block = 4 waves x 64 rows.
// Wave w: rows blockIdx*64 + w*16 .. +15, all CT*16 cols. K-loop: 4 panels of 32.
// A-frag: A[m=lane&15][k=quad*8+j] straight from global (16B contiguous).
// B-frag: B[k=quad*8+j][n=lane&15] from LDS Wt (row stride 136 -> 2-way bank alias, free).
template<int CT, int WCOUT, int OUTC>
__global__ __launch_bounds__(256) void k_gemm_mfma(const unsigned short* __restrict__ xb,
                                                   const unsigned short* __restrict__ wt,
                                                   const float* __restrict__ onorm,
                                                   unsigned short* __restrict__ outb){
  __shared__ unsigned short Wl[CT * 16][136];
  const int t = threadIdx.x;
  const int lane = t & 63;
  const int w = t >> 6;
  const int ln15 = lane & 15;
  const int quad = lane >> 4;

  // stage Wt into LDS (row stride 136)
  {
    const uint4* w4 = (const uint4*)wt;      // 16 uint4 per 128-bf16 row
    #pragma unroll
    for (int i = 0; i < CT; ++i){
      int idx = t + i * 256;                 // CT*256 uint4 total
      int row = idx >> 4, q = idx & 15;
      *(uint4*)&Wl[row][q * 8] = w4[idx];
    }
  }
  __syncthreads();

  f32x4 acc[CT];
  #pragma unroll
  for (int ct = 0; ct < CT; ++ct) acc[ct] = (f32x4){0.f, 0.f, 0.f, 0.f};

  const unsigned short* xrow = xb + (size_t)(blockIdx.x * 64 + w * 16 + ln15) * 128;
  #pragma unroll
  for (int kp = 0; kp < 4; ++kp){
    bf16x8 a = *(const bf16x8*)(xrow + kp * 32 + quad * 8);
    #pragma unroll
    for (int ct = 0; ct < CT; ++ct){
      bf16x8 b = *(const bf16x8*)&Wl[ct * 16 + ln15][kp * 32 + quad * 8];
      acc[ct] = __builtin_amdgcn_mfma_f32_16x16x32_bf16(a, b, acc[ct], 0, 0, 0);
    }
  }

  // epilogue: C/D layout col=lane&15, row=quad*4+reg
  const int rowbase = blockIdx.x * 64 + w * 16 + quad * 4;
  float o[4];
  #pragma unroll
  for (int j = 0; j < 4; ++j){
    int r = rowbase + j;
    o[j] = (r < N_NODES) ? onorm[r] : 0.f;
  }
  #pragma unroll
  for (int ct = 0; ct < CT; ++ct){
    int col = ct * 16 + ln15;
    if (WCOUT < CT * 16 && col >= WCOUT) continue;
    #pragma unroll
    for (int j = 0; j < 4; ++j){
      int r = rowbase + j;
      if (r < N_NODES)
        outb[(size_t)r * OUTC + col] = bf1(acc[ct][j] * o[j]);
    }
  }
}

// ---------------- wave-per-node bf16 gather-aggregate ----------------
// htmp rows are CW bf16 (CU = CW/2 u32); lane l owns cols {2l, 2l+1}.
template<int CW, bool RELU, bool OUTBF>
__global__ __launch_bounds__(256) void k_agg(const unsigned* __restrict__ htmp,
                                             const int* __restrict__ rowptr,
                                             const int* __restrict__ esrc,
                                             const float* __restrict__ inorm,
                                             const float* __restrict__ bias,
                                             void* __restrict__ outv){
  constexpr int CU = CW / 2;              // 64 or 20
  const int wave = threadIdx.x >> 6;
  const int lane = threadIdx.x & 63;
  const int node = blockIdx.x * 4 + wave;
  if (node >= N_NODES) return;
  const int start = rowptr[node], end = rowptr[node + 1];
  float a0 = 0.f, a1 = 0.f, b0 = 0.f, b1 = 0.f,
        c0 = 0.f, c1 = 0.f, d0 = 0.f, d1 = 0.f;
  for (int e0 = start; e0 < end; e0 += 64){
    const int n = min(64, end - e0);
    int el = (lane < n) ? esrc[e0 + lane] : 0;
    int j = 0;
    for (; j + 4 <= n; j += 4){
      int s0 = __shfl(el, j);
      int s1 = __shfl(el, j + 1);
      int s2 = __shfl(el, j + 2);
      int s3 = __shfl(el, j + 3);
      if (lane < CU){
        unsigned u0 = htmp[(size_t)s0 * CU + lane];
        unsigned u1 = htmp[(size_t)s1 * CU + lane];
        unsigned u2 = htmp[(size_t)s2 * CU + lane];
        unsigned u3 = htmp[(size_t)s3 * CU + lane];
        a0 += bflo(u0); a1 += bfhi(u0);
        b0 += bflo(u1); b1 += bfhi(u1);
        c0 += bflo(u2); c1 += bfhi(u2);
        d0 += bflo(u3); d1 += bfhi(u3);
      }
    }
    for (; j < n; ++j){
      int s0 = __shfl(el, j);
      if (lane < CU){
        unsigned u0 = htmp[(size_t)s0 * CU + lane];
        a0 += bflo(u0); a1 += bfhi(u0);
      }
    }
  }
  if (lane < CU){
    float sc = inorm[node];
    float y0 = ((a0 + b0) + (c0 + d0)) * sc + bias[2 * lane];
    float y1 = ((a1 + b1) + (c1 + d1)) * sc + bias[2 * lane + 1];
    if (RELU){ y0 = fmaxf(y0, 0.f); y1 = fmaxf(y1, 0.f); }
    if (OUTBF){
      ((unsigned*)outv)[(size_t)node * CU + lane] = pkbf(y0, y1);
    } else {
      float2 v; v.x = y0; v.y = y1;
      *(float2*)&((float*)outv)[(size_t)node * CW + 2 * lane] = v;
    }
  }
}

// ---------------- launch ----------------
extern "C" void kernel_launch(void* const* d_in, const int* in_sizes, int n_in,
                              void* d_out, int out_size, void* d_ws, size_t ws_size,
                              hipStream_t stream){
  const float* feat = (const float*)d_in[0];
  const float* W1   = (const float*)d_in[1];
  const float* b1   = (const float*)d_in[2];
  const float* W2   = (const float*)d_in[3];
  const float* b2   = (const float*)d_in[4];
  const float* W3   = (const float*)d_in[5];
  const float* b3   = (const float*)d_in[6];
  const int* src = (const int*)d_in[7];
  const int* dst = (const int*)d_in[8];
  float* out = (float*)d_out;

  char* ws = (char*)d_ws;
  float*    onorm   = (float*)   (ws + OFF_ONORM);
  float*    inorm   = (float*)   (ws + OFF_INORM);
  int*      rowptr  = (int*)     (ws + OFF_ROWPTR);
  unsigned* din     = (unsigned*)(ws + OFF_DIN);
  unsigned* bsum    = (unsigned*)(ws + OFF_BSUM);
  unsigned* boff    = (unsigned*)(ws + OFF_BOFF);
  unsigned* wt1     = (unsigned*)(ws + OFF_WT1);
  unsigned* wt2     = (unsigned*)(ws + OFF_WT2);
  unsigned* wt3     = (unsigned*)(ws + OFF_WT3);
  int*      esrc    = (int*)     (ws + OFF_ESRC);
  unsigned short* featb = (unsigned short*)(ws + OFF_FEATB);
  unsigned short* htmp  = (unsigned short*)(ws + OFF_HTMP);
  unsigned short* xbuf  = (unsigned short*)(ws + OFF_XBUF);
  unsigned* part    = (unsigned*)(ws + OFF_PART);   // aliases htmp (dead before GEMM1)

  const int NB = (N_NODES + 255) / 256;

  // ---- input prep (independent of CSR) ----
  k_cvt<<<6250, 256, 0, stream>>>(feat, (unsigned*)featb);   // 1.6M float4 exactly
  k_prep_w<128, 8><<<32, 256, 0, stream>>>(W1, wt1);
  k_prep_w<128, 8><<<32, 256, 0, stream>>>(W2, wt2);
  k_prep_w< 40, 4><<<16, 256, 0, stream>>>(W3, wt3);

  // ---- CSR build: LDS atomics only ----
  k_hist_lds    <<<dim3(NS, NRANGE, 2), 1024, 0, stream>>>(src, dst, part);
  k_reduce_norms<<<NB, 256, 0, stream>>>(part, din, inorm, onorm);
  k_scan1       <<<NBLK, 1024, 0, stream>>>(din, rowptr, bsum);
  k_scan2       <<<1, 64, 0, stream>>>(bsum, boff);
  k_scan3       <<<NBLK, 1024, 0, stream>>>(rowptr, boff);
  k_base        <<<NB, 256, 0, stream>>>(part, rowptr);
  k_scatter_lds <<<dim3(NS, NRANGE), 1024, 0, stream>>>(src, dst, part, esrc);

  const int GB = XPAD / 64;            // 782
  const int AB = (N_NODES + 3) / 4;
  // layer 1
  k_gemm_mfma<8, 128, 128><<<GB, 256, 0, stream>>>(featb, (unsigned short*)wt1, onorm, htmp);
  k_agg<128, true, true ><<<AB, 256, 0, stream>>>((unsigned*)htmp, rowptr, esrc, inorm, b1, xbuf);
  // layer 2
  k_gemm_mfma<8, 128, 128><<<GB, 256, 0, stream>>>(xbuf, (unsigned short*)wt2, onorm, htmp);
  k_agg<128, true, true ><<<AB, 256, 0, stream>>>((unsigned*)htmp, rowptr, esrc, inorm, b2, xbuf);
  // layer 3 (40 real cols, 64 computed)
  k_gemm_mfma<4, 40, 40><<<GB, 256, 0, stream>>>(xbuf, (unsigned short*)wt3, onorm, htmp);
  k_agg<40, false, false><<<AB, 256, 0, stream>>>((unsigned*)htmp, rowptr, esrc, inorm, b3, out);
}

// Round 9
// 248.718 us; speedup vs baseline: 2.0084x; 1.1233x over previous
//
#include <hip/hip_runtime.h>
#include <hip/hip_bf16.h>

#define N_NODES 50000
#define N_EDGES 800000
#define FEAT    128
#define HID     128
#define NCLS    40
#define XPAD    50048            // N rounded up to 64 (GEMM tiles read unguarded)

#define RANGE   12500            // nodes per LDS-histogram range (50 KB of u32)
#define NRANGE  4                // 4 * 12500 = 50000
#define NS      32               // edge slices (hist grid = NS*4*2 = 256 blocks = 1/CU)
#define SLICE   (N_EDGES / NS)   // 25000 edges per slice
#define NBLK    49               // scan blocks: ceil(50000/1024)

// ---------------- workspace layout ----------------
static constexpr size_t ALIGNB = 256;
static constexpr size_t aln(size_t x){ return (x + ALIGNB - 1) & ~(ALIGNB - 1); }
static constexpr size_t OFF_ONORM   = 0;
static constexpr size_t OFF_INORM   = OFF_ONORM + aln((size_t)N_NODES * 4);
static constexpr size_t OFF_ROWPTR  = OFF_INORM + aln((size_t)N_NODES * 4);
static constexpr size_t OFF_BSUM    = OFF_ROWPTR + aln((size_t)(N_NODES + 1) * 4);
static constexpr size_t OFF_BOFF    = OFF_BSUM + aln(64 * 4);
static constexpr size_t OFF_WT1     = OFF_BOFF + aln(64 * 4);
static constexpr size_t OFF_WT2     = OFF_WT1 + aln((size_t)128 * 128 * 2);
static constexpr size_t OFF_WT3     = OFF_WT2 + aln((size_t)128 * 128 * 2);
static constexpr size_t OFF_ESRC    = OFF_WT3 + aln((size_t)64 * 128 * 2);
static constexpr size_t OFF_HTMP    = OFF_ESRC + aln((size_t)N_EDGES * 4);
static constexpr size_t OFF_XBUF    = OFF_HTMP + aln((size_t)XPAD * 128 * 2);
// partial histograms alias htmp (dead before GEMM1 writes htmp):
// part[z][r][s][RANGE] = 2*4*32*12500*4 = 12.8 MB <= htmp region (12.81 MB)
static constexpr size_t OFF_PART    = OFF_HTMP;

// ---------------- helpers ----------------
__device__ __forceinline__ float bflo(unsigned u){
  union { unsigned i; float f; } c; c.i = u << 16; return c.f;
}
__device__ __forceinline__ float bfhi(unsigned u){
  union { unsigned i; float f; } c; c.i = u & 0xffff0000u; return c.f;
}
__device__ __forceinline__ unsigned pkbf(float a, float b){
  union { __hip_bfloat16 h; unsigned short u; } ca, cb;
  ca.h = __float2bfloat16(a); cb.h = __float2bfloat16(b);
  return ((unsigned)cb.u << 16) | (unsigned)ca.u;
}
__device__ __forceinline__ unsigned short bf1(float a){
  union { __hip_bfloat16 h; unsigned short u; } c;
  c.h = __float2bfloat16(a); return c.u;
}

typedef __attribute__((ext_vector_type(8))) short bf16x8;
typedef __attribute__((ext_vector_type(4))) float f32x4;

// ---------------- all weights fp32 -> transposed bf16, one kernel ----------------
// Wt layout: [c][kp] u32 (kp = packed k-pair), 64 kp per c.
__global__ void k_prep_all(const float* __restrict__ W1, const float* __restrict__ W2,
                           const float* __restrict__ W3,
                           unsigned* __restrict__ wt1, unsigned* __restrict__ wt2,
                           unsigned* __restrict__ wt3){
  int b = blockIdx.x, t = threadIdx.x;
  const float* W; unsigned* Wt; int WC; int idx;
  if (b < 32)      { W = W1; Wt = wt1; WC = 128; idx = b * 256 + t; }
  else if (b < 64) { W = W2; Wt = wt2; WC = 128; idx = (b - 32) * 256 + t; }
  else             { W = W3; Wt = wt3; WC = 40;  idx = (b - 64) * 256 + t; }
  int c = idx >> 6, kp = idx & 63;
  float v0 = (c < WC) ? W[(size_t)(2 * kp)     * WC + c] : 0.f;
  float v1 = (c < WC) ? W[(size_t)(2 * kp + 1) * WC + c] : 0.f;
  Wt[idx] = pkbf(v0, v1);
}

// ---------------- LDS histogram (no global atomics anywhere) ----------------
// grid = (NS, NRANGE, 2); z selects dst (in-deg) vs src (out-deg).
__global__ __launch_bounds__(1024) void k_hist_lds(const int* __restrict__ src,
                                                   const int* __restrict__ dst,
                                                   unsigned* __restrict__ part){
  __shared__ unsigned h[RANGE];
  const int s = blockIdx.x, r = blockIdx.y, z = blockIdx.z;
  const int* __restrict__ idx = z ? src : dst;
  const int lo = r * RANGE;
  for (int i = threadIdx.x; i < RANGE; i += 1024) h[i] = 0;
  __syncthreads();
  const int e0 = s * SLICE;
  for (int e = e0 + threadIdx.x; e < e0 + SLICE; e += 1024){
    int v = idx[e] - lo;
    if ((unsigned)v < RANGE) atomicAdd(&h[v], 1u);   // LDS atomic
  }
  __syncthreads();
  unsigned* p = part + (((size_t)z * NRANGE + r) * NS + s) * RANGE;
  for (int i = threadIdx.x; i < RANGE; i += 1024) p[i] = h[i];
}

// ---------------- fused: reduce partials -> norms + local block scan ----------------
__global__ __launch_bounds__(1024) void k_scan1(const unsigned* __restrict__ part,
                                                int* __restrict__ rowptr,
                                                unsigned* __restrict__ bsum,
                                                float* __restrict__ inorm,
                                                float* __restrict__ onorm){
  __shared__ int wsum[16];
  const int t = threadIdx.x, lane = t & 63, w = t >> 6;
  const int i = blockIdx.x * 1024 + t;
  int v = 0;
  if (i < N_NODES){
    int r = i / RANGE, off = i % RANGE;
    const unsigned* pi = part + ((size_t)r * NS) * RANGE + off;
    const unsigned* po = part + (((size_t)NRANGE + r) * NS) * RANGE + off;
    unsigned si = 0, so = 0;
    #pragma unroll 8
    for (int s = 0; s < NS; ++s){
      si += pi[(size_t)s * RANGE];
      so += po[(size_t)s * RANGE];
    }
    inorm[i] = rsqrtf(fmaxf((float)si, 1.0f));
    onorm[i] = rsqrtf(fmaxf((float)so, 1.0f));
    v = (int)si;
  }
  int x = v;
  #pragma unroll
  for (int off = 1; off < 64; off <<= 1){
    int y = __shfl_up(x, off, 64);
    if (lane >= off) x += y;
  }
  if (lane == 63) wsum[w] = x;
  __syncthreads();
  if (w == 0 && lane < 16){
    int s = wsum[lane];
    #pragma unroll
    for (int off = 1; off < 16; off <<= 1){
      int y = __shfl_up(s, off, 64);
      if (lane >= off) s += y;
    }
    wsum[lane] = s;
  }
  __syncthreads();
  int woff = (w > 0) ? wsum[w - 1] : 0;
  if (i < N_NODES) rowptr[i] = woff + x - v;
  if (t == 0) bsum[blockIdx.x] = (unsigned)wsum[15];
}

// ---------------- scan of block sums (single wave) ----------------
__global__ void k_scan2(const unsigned* __restrict__ bsum, unsigned* __restrict__ boff){
  const int t = threadIdx.x;                 // 64 threads
  int v = (t < NBLK) ? (int)bsum[t] : 0;
  int x = v;
  #pragma unroll
  for (int off = 1; off < 64; off <<= 1){
    int y = __shfl_up(x, off, 64);
    if (t >= off) x += y;
  }
  if (t < NBLK) boff[t] = (unsigned)(x - v);
  if (t == NBLK - 1) boff[NBLK] = (unsigned)x;   // grand total
}

// ---------------- fused: add block offsets + build per-(range,slice) base cursors ----------------
__global__ __launch_bounds__(1024) void k_scan3(int* __restrict__ rowptr,
                                                const unsigned* __restrict__ boff,
                                                unsigned* __restrict__ part){
  const int i = blockIdx.x * 1024 + threadIdx.x;
  if (i < N_NODES){
    int rp = rowptr[i] + (int)boff[blockIdx.x];
    rowptr[i] = rp;
    int r = i / RANGE, off = i % RANGE;
    unsigned* p = part + ((size_t)r * NS) * RANGE + off;
    unsigned run = (unsigned)rp;
    #pragma unroll 8
    for (int s = 0; s < NS; ++s){
      unsigned c = p[(size_t)s * RANGE];
      p[(size_t)s * RANGE] = run;
      run += c;
    }
  } else if (i == N_NODES) rowptr[i] = (int)boff[NBLK];
}

// ---------------- scatter edges into CSR slots (LDS cursor atomics) ----------------
// grid = (NS, NRANGE)
__global__ __launch_bounds__(1024) void k_scatter_lds(const int* __restrict__ src,
                                                      const int* __restrict__ dst,
                                                      const unsigned* __restrict__ part,
                                                      int* __restrict__ esrc){
  __shared__ unsigned cur[RANGE];
  const int s = blockIdx.x, r = blockIdx.y;
  const int lo = r * RANGE;
  const unsigned* p = part + ((size_t)r * NS + s) * RANGE;
  for (int i = threadIdx.x; i < RANGE; i += 1024) cur[i] = p[i];
  __syncthreads();
  const int e0 = s * SLICE;
  for (int e = e0 + threadIdx.x; e < e0 + SLICE; e += 1024){
    int v = dst[e] - lo;
    if ((unsigned)v < RANGE){
      unsigned pos = atomicAdd(&cur[v], 1u);          // LDS atomic
      esrc[pos] = src[e];
    }
  }
}

// ---------------- MFMA GEMM: out[r][c] = bf16( onorm[r] * sum_k X[r][k] * W[k][c] ) ----------------
// X: bf16 [XPAD][128] or fp32 [N][128] (IN_F32: converted in-register, row clamped).
// Wt: bf16 [CT*16][128] (c-major). Block = 4 waves x 64 rows.
// A-frag: A[m=lane&15][k=quad*8+j] contiguous from global.
// B-frag: B[k=quad*8+j][n=lane&15] from LDS Wt (row stride 136 -> 2-way alias, free).
template<int CT, int WCOUT, int OUTC, bool IN_F32>
__global__ __launch_bounds__(256) void k_gemm_mfma(const void* __restrict__ xin,
                                                   const unsigned short* __restrict__ wt,
                                                   const float* __restrict__ onorm,
                                                   unsigned short* __restrict__ outb){
  __shared__ unsigned short Wl[CT * 16][136];
  const int t = threadIdx.x;
  const int lane = t & 63;
  const int w = t >> 6;
  const int ln15 = lane & 15;
  const int quad = lane >> 4;

  // stage Wt into LDS (row stride 136)
  {
    const uint4* w4 = (const uint4*)wt;      // 16 uint4 per 128-bf16 row
    #pragma unroll
    for (int i = 0; i < CT; ++i){
      int idx = t + i * 256;                 // CT*256 uint4 total
      int row = idx >> 4, q = idx & 15;
      *(uint4*)&Wl[row][q * 8] = w4[idx];
    }
  }
  __syncthreads();

  f32x4 acc[CT];
  #pragma unroll
  for (int ct = 0; ct < CT; ++ct) acc[ct] = (f32x4){0.f, 0.f, 0.f, 0.f};

  const int xr = min(blockIdx.x * 64 + w * 16 + ln15, N_NODES - 1);  // clamp: padded rows unused
  #pragma unroll
  for (int kp = 0; kp < 4; ++kp){
    bf16x8 a;
    if (IN_F32){
      const float4* x4 = (const float4*)xin + (size_t)xr * 32;
      float4 p0 = x4[kp * 8 + quad * 2];
      float4 p1 = x4[kp * 8 + quad * 2 + 1];
      union { bf16x8 v; unsigned u[4]; } ua;
      ua.u[0] = pkbf(p0.x, p0.y); ua.u[1] = pkbf(p0.z, p0.w);
      ua.u[2] = pkbf(p1.x, p1.y); ua.u[3] = pkbf(p1.z, p1.w);
      a = ua.v;
    } else {
      const unsigned short* xrow = (const unsigned short*)xin + (size_t)xr * 128;
      a = *(const bf16x8*)(xrow + kp * 32 + quad * 8);
    }
    #pragma unroll
    for (int ct = 0; ct < CT; ++ct){
      bf16x8 b = *(const bf16x8*)&Wl[ct * 16 + ln15][kp * 32 + quad * 8];
      acc[ct] = __builtin_amdgcn_mfma_f32_16x16x32_bf16(a, b, acc[ct], 0, 0, 0);
    }
  }

  // epilogue: C/D layout col=lane&15, row=quad*4+reg
  const int rowbase = blockIdx.x * 64 + w * 16 + quad * 4;
  float o[4];
  #pragma unroll
  for (int j = 0; j < 4; ++j){
    int r = rowbase + j;
    o[j] = (r < N_NODES) ? onorm[r] : 0.f;
  }
  #pragma unroll
  for (int ct = 0; ct < CT; ++ct){
    int col = ct * 16 + ln15;
    if (WCOUT < CT * 16 && col >= WCOUT) continue;
    #pragma unroll
    for (int j = 0; j < 4; ++j){
      int r = rowbase + j;
      if (r < N_NODES)
        outb[(size_t)r * OUTC + col] = bf1(acc[ct][j] * o[j]);
    }
  }
}

// ---------------- wave-per-node bf16 gather-aggregate ----------------
// htmp rows are CW bf16 (CU = CW/2 u32); lane l owns cols {2l, 2l+1}.
template<int CW, bool RELU, bool OUTBF>
__global__ __launch_bounds__(256) void k_agg(const unsigned* __restrict__ htmp,
                                             const int* __restrict__ rowptr,
                                             const int* __restrict__ esrc,
                                             const float* __restrict__ inorm,
                                             const float* __restrict__ bias,
                                             void* __restrict__ outv){
  constexpr int CU = CW / 2;              // 64 or 20
  const int wave = threadIdx.x >> 6;
  const int lane = threadIdx.x & 63;
  const int node = blockIdx.x * 4 + wave;
  if (node >= N_NODES) return;
  const int start = rowptr[node], end = rowptr[node + 1];
  float aL[4] = {0.f, 0.f, 0.f, 0.f};
  float aH[4] = {0.f, 0.f, 0.f, 0.f};
  for (int e0 = start; e0 < end; e0 += 64){
    const int n = min(64, end - e0);
    int el = (lane < n) ? esrc[e0 + lane] : 0;
    int j = 0;
    for (; j + 8 <= n; j += 8){
      int ss[8];
      #pragma unroll
      for (int q = 0; q < 8; ++q) ss[q] = __shfl(el, j + q);
      if (lane < CU){
        unsigned uu[8];
        #pragma unroll
        for (int q = 0; q < 8; ++q) uu[q] = htmp[(size_t)ss[q] * CU + lane];
        #pragma unroll
        for (int q = 0; q < 8; ++q){ aL[q & 3] += bflo(uu[q]); aH[q & 3] += bfhi(uu[q]); }
      }
    }
    for (; j + 4 <= n; j += 4){
      int ss[4];
      #pragma unroll
      for (int q = 0; q < 4; ++q) ss[q] = __shfl(el, j + q);
      if (lane < CU){
        unsigned uu[4];
        #pragma unroll
        for (int q = 0; q < 4; ++q) uu[q] = htmp[(size_t)ss[q] * CU + lane];
        #pragma unroll
        for (int q = 0; q < 4; ++q){ aL[q] += bflo(uu[q]); aH[q] += bfhi(uu[q]); }
      }
    }
    for (; j < n; ++j){
      int s0 = __shfl(el, j);
      if (lane < CU){
        unsigned u0 = htmp[(size_t)s0 * CU + lane];
        aL[0] += bflo(u0); aH[0] += bfhi(u0);
      }
    }
  }
  if (lane < CU){
    float sc = inorm[node];
    float y0 = ((aL[0] + aL[1]) + (aL[2] + aL[3])) * sc + bias[2 * lane];
    float y1 = ((aH[0] + aH[1]) + (aH[2] + aH[3])) * sc + bias[2 * lane + 1];
    if (RELU){ y0 = fmaxf(y0, 0.f); y1 = fmaxf(y1, 0.f); }
    if (OUTBF){
      ((unsigned*)outv)[(size_t)node * CU + lane] = pkbf(y0, y1);
    } else {
      float2 v; v.x = y0; v.y = y1;
      *(float2*)&((float*)outv)[(size_t)node * CW + 2 * lane] = v;
    }
  }
}

// ---------------- launch ----------------
extern "C" void kernel_launch(void* const* d_in, const int* in_sizes, int n_in,
                              void* d_out, int out_size, void* d_ws, size_t ws_size,
                              hipStream_t stream){
  const float* feat = (const float*)d_in[0];
  const float* W1   = (const float*)d_in[1];
  const float* b1   = (const float*)d_in[2];
  const float* W2   = (const float*)d_in[3];
  const float* b2   = (const float*)d_in[4];
  const float* W3   = (const float*)d_in[5];
  const float* b3   = (const float*)d_in[6];
  const int* src = (const int*)d_in[7];
  const int* dst = (const int*)d_in[8];
  float* out = (float*)d_out;

  char* ws = (char*)d_ws;
  float*    onorm   = (float*)   (ws + OFF_ONORM);
  float*    inorm   = (float*)   (ws + OFF_INORM);
  int*      rowptr  = (int*)     (ws + OFF_ROWPTR);
  unsigned* bsum    = (unsigned*)(ws + OFF_BSUM);
  unsigned* boff    = (unsigned*)(ws + OFF_BOFF);
  unsigned* wt1     = (unsigned*)(ws + OFF_WT1);
  unsigned* wt2     = (unsigned*)(ws + OFF_WT2);
  unsigned* wt3     = (unsigned*)(ws + OFF_WT3);
  int*      esrc    = (int*)     (ws + OFF_ESRC);
  unsigned short* htmp = (unsigned short*)(ws + OFF_HTMP);
  unsigned short* xbuf = (unsigned short*)(ws + OFF_XBUF);
  unsigned* part    = (unsigned*)(ws + OFF_PART);   // aliases htmp (dead before GEMM1)

  // ---- prep + CSR build (LDS atomics only) ----
  k_prep_all    <<<80, 256, 0, stream>>>(W1, W2, W3, wt1, wt2, wt3);
  k_hist_lds    <<<dim3(NS, NRANGE, 2), 1024, 0, stream>>>(src, dst, part);
  k_scan1       <<<NBLK, 1024, 0, stream>>>(part, rowptr, bsum, inorm, onorm);
  k_scan2       <<<1, 64, 0, stream>>>(bsum, boff);
  k_scan3       <<<NBLK, 1024, 0, stream>>>(rowptr, boff, part);
  k_scatter_lds <<<dim3(NS, NRANGE), 1024, 0, stream>>>(src, dst, part, esrc);

  const int GB = XPAD / 64;            // 782
  const int AB = (N_NODES + 3) / 4;
  // layer 1 (fp32 feat read directly, converted in-register)
  k_gemm_mfma<8, 128, 128, true ><<<GB, 256, 0, stream>>>(feat, (unsigned short*)wt1, onorm, htmp);
  k_agg<128, true, true ><<<AB, 256, 0, stream>>>((unsigned*)htmp, rowptr, esrc, inorm, b1, xbuf);
  // layer 2
  k_gemm_mfma<8, 128, 128, false><<<GB, 256, 0, stream>>>(xbuf, (unsigned short*)wt2, onorm, htmp);
  k_agg<128, true, true ><<<AB, 256, 0, stream>>>((unsigned*)htmp, rowptr, esrc, inorm, b2, xbuf);
  // layer 3 (40 real cols, 64 computed)
  k_gemm_mfma<4, 40, 40, false><<<GB, 256, 0, stream>>>(xbuf, (unsigned short*)wt3, onorm, htmp);
  k_agg<40, false, false><<<AB, 256, 0, stream>>>((unsigned*)htmp, rowptr, esrc, inorm, b3, out);
}